// Round 5
// baseline (239.393 us; speedup 1.0000x reference)
//
#include <hip/hip_runtime.h>
#include <cstdint>

#define B_SZ 8192
#define D_SZ 512
#define K_SZ 2048
#define EPSV 1e-8f
// 1/TEMP
#define INV_T 2.0f

typedef short short8 __attribute__((ext_vector_type(8)));
typedef float floatx4 __attribute__((ext_vector_type(4)));

// fp32 -> bf16 round-to-nearest-even (inputs are finite random normals; no NaN path)
__device__ __forceinline__ unsigned short f2bf(float f) {
    unsigned int u = __float_as_uint(f);
    u += 0x7FFFu + ((u >> 16) & 1u);
    return (unsigned short)(u >> 16);
}

// ---------------------------------------------------------------------------
// Kernel 1 (merged prep+gather):
//  blocks [0,2048):  per-row norms of z_i/z_j, positive logit, z_i -> bf16 A
//  blocks [2048,3072): gather 2K=4096 rows (c_k, c_k+1) of z_j -> bf16 G + norms
// One wave per row in both halves.
// ---------------------------------------------------------------------------
__global__ __launch_bounds__(256) void k_prep(
    const float* __restrict__ zi, const float* __restrict__ zj,
    const int* __restrict__ perm,
    float* __restrict__ ni_arr, float* __restrict__ pos_arr,
    unsigned short* __restrict__ A,
    float* __restrict__ njc, unsigned short* __restrict__ G)
{
    int w = threadIdx.x >> 6, l = threadIdx.x & 63;
    if (blockIdx.x < 2048) {
        int row = blockIdx.x * 4 + w;
        const float4* zi4 = (const float4*)(zi + (size_t)row * D_SZ);
        const float4* zj4 = (const float4*)(zj + (size_t)row * D_SZ);
        float4 a0 = zi4[2 * l], a1 = zi4[2 * l + 1];
        float4 b0 = zj4[2 * l], b1 = zj4[2 * l + 1];
        float si = a0.x * a0.x + a0.y * a0.y + a0.z * a0.z + a0.w * a0.w
                 + a1.x * a1.x + a1.y * a1.y + a1.z * a1.z + a1.w * a1.w;
        float sj = b0.x * b0.x + b0.y * b0.y + b0.z * b0.z + b0.w * b0.w
                 + b1.x * b1.x + b1.y * b1.y + b1.z * b1.z + b1.w * b1.w;
        float dd = a0.x * b0.x + a0.y * b0.y + a0.z * b0.z + a0.w * b0.w
                 + a1.x * b1.x + a1.y * b1.y + a1.z * b1.z + a1.w * b1.w;
        for (int m = 1; m < 64; m <<= 1) {
            si += __shfl_xor(si, m);
            sj += __shfl_xor(sj, m);
            dd += __shfl_xor(dd, m);
        }
        if (l == 0) {
            float ni = sqrtf(si), nj = sqrtf(sj);
            ni_arr[row] = ni;
            pos_arr[row] = dd / fmaxf(ni * nj, EPSV) * INV_T;
        }
        union { unsigned short u[8]; uint4 v; } pk;
        pk.u[0] = f2bf(a0.x); pk.u[1] = f2bf(a0.y); pk.u[2] = f2bf(a0.z); pk.u[3] = f2bf(a0.w);
        pk.u[4] = f2bf(a1.x); pk.u[5] = f2bf(a1.y); pk.u[6] = f2bf(a1.z); pk.u[7] = f2bf(a1.w);
        *(uint4*)(A + (size_t)row * D_SZ + l * 8) = pk.v;
    } else {
        int g = (blockIdx.x - 2048) * 4 + w;        // 0..4095
        int c = perm[g >> 1] + (g & 1);             // actual z_j row
        const float4* src = (const float4*)(zj + (size_t)c * D_SZ);
        float4 a0 = src[2 * l], a1 = src[2 * l + 1];
        float s = a0.x * a0.x + a0.y * a0.y + a0.z * a0.z + a0.w * a0.w
                + a1.x * a1.x + a1.y * a1.y + a1.z * a1.z + a1.w * a1.w;
        for (int m = 1; m < 64; m <<= 1) s += __shfl_xor(s, m);
        if (l == 0) njc[g] = sqrtf(s);
        union { unsigned short u[8]; uint4 v; } pk;
        pk.u[0] = f2bf(a0.x); pk.u[1] = f2bf(a0.y); pk.u[2] = f2bf(a0.z); pk.u[3] = f2bf(a0.w);
        pk.u[4] = f2bf(a1.x); pk.u[5] = f2bf(a1.y); pk.u[6] = f2bf(a1.z); pk.u[7] = f2bf(a1.w);
        *(uint4*)(G + (size_t)g * D_SZ + l * 8) = pk.v;
    }
}

// ---------------------------------------------------------------------------
// Kernel 2: bf16 MFMA GEMM S = A (8192x512) . G^T (512x4096), fused epilogue.
// NO LDS, NO BARRIERS: both operands load global->VGPR directly in MFMA
// fragment layout (16-row x 64B wave-loads; per-block per-dblk working set
// 32 KB -> L1-resident, so the 2x cross-wave re-read is L1-served).
// Register double-buffer: dblk+1's 16 frag loads are issued before dblk's
// MFMAs; compiler's fine-grained vmcnt covers them with ~620 cyc of
// matrix-pipe work. Manually 2x-unrolled so buffer indices are constants.
// 128x128 tile, 256 threads (2x2 waves of 64x64), 16x16x32 MFMA.
// ---------------------------------------------------------------------------
__global__ __launch_bounds__(256) void k_gemm(
    const unsigned short* __restrict__ A,   // [8192][512] bf16
    const unsigned short* __restrict__ G,   // [4096][512] bf16
    const int* __restrict__ perm,           // [2048]
    const float* __restrict__ ni_arr,       // [8192]
    const float* __restrict__ njc,          // [4096]
    const float* __restrict__ pos_arr,      // [8192]
    float* __restrict__ ws_pe, float* __restrict__ ws_pc)  // [8192][64]
{
    const int tid = threadIdx.x;
    const int l = tid & 63, w = tid >> 6;
    const int wm = w >> 1, wn = w & 1;
    const int q = l >> 4, ln = l & 15;
    const int rowBase = blockIdx.y * 128;
    const int colBase = blockIdx.x * 128;

    // fragment lane bases: row = base + t*16 + ln, k = dblk*64 + kc*32 + q*8
    const unsigned short* aBase = A + (size_t)(rowBase + wm * 64 + ln) * D_SZ + q * 8;
    const unsigned short* gBase = G + (size_t)(colBase + wn * 64 + ln) * D_SZ + q * 8;

    floatx4 acc[4][4] = {};
    short8 bA0[2][4], bG0[2][4], bA1[2][4], bG1[2][4];

    auto load_into = [&](short8 (&bA)[2][4], short8 (&bG)[2][4], int dblk) {
        #pragma unroll
        for (int kc = 0; kc < 2; ++kc)
            #pragma unroll
            for (int t = 0; t < 4; ++t) {
                bA[kc][t] = *(const short8*)(aBase + (size_t)(t * 16) * D_SZ
                                             + (size_t)dblk * 64 + kc * 32);
                bG[kc][t] = *(const short8*)(gBase + (size_t)(t * 16) * D_SZ
                                             + (size_t)dblk * 64 + kc * 32);
            }
    };
    auto compute = [&](short8 (&bA)[2][4], short8 (&bG)[2][4]) {
        #pragma unroll
        for (int kc = 0; kc < 2; ++kc)
            #pragma unroll
            for (int tm = 0; tm < 4; ++tm)
                #pragma unroll
                for (int tn = 0; tn < 4; ++tn)
                    acc[tm][tn] = __builtin_amdgcn_mfma_f32_16x16x32_bf16(
                        bA[kc][tm], bG[kc][tn], acc[tm][tn], 0, 0, 0);
    };

    load_into(bA0, bG0, 0);
    #pragma unroll 1
    for (int d2 = 0; d2 < 4; ++d2) {
        load_into(bA1, bG1, d2 * 2 + 1);        // prefetch odd dblk
        compute(bA0, bG0);                      // compute even dblk
        if (d2 < 3)
            load_into(bA0, bG0, d2 * 2 + 2);    // prefetch next even dblk
        compute(bA1, bG1);                      // compute odd dblk
    }

    // ---- fused epilogue ----
    // C/D layout: col = ln, row = q*4 + reg
    const int cb = blockIdx.x * 2 + wn;     // 64-col chunk index, 0..63
    float njv[4]; int cv[4], shv[4];
    #pragma unroll
    for (int tn = 0; tn < 4; ++tn) {
        int g = colBase + wn * 64 + tn * 16 + ln;
        cv[tn] = perm[g >> 1];
        shv[tn] = g & 1;
        njv[tn] = njc[g];
    }
    #pragma unroll
    for (int tm = 0; tm < 4; ++tm) {
        int row0 = rowBase + wm * 64 + tm * 16 + q * 4;
        #pragma unroll
        for (int r = 0; r < 4; ++r) {
            int row = row0 + r;
            float niv = ni_arr[row];
            float pv = pos_arr[row];
            float pe = 0.f, pc = 0.f;
            #pragma unroll
            for (int tn = 0; tn < 4; ++tn) {
                float v = acc[tm][tn][r];
                float logit = v * INV_T / fmaxf(niv * njv[tn], EPSV);
                // row uses column c+1 iff c >= row; our gathered col is c+shv
                bool use = ((cv[tn] >= row) ? 1 : 0) == shv[tn];
                if (use) {
                    pe += __expf(logit);
                    pc += (logit > pv) ? 1.f : 0.f;
                }
            }
            // reduce over the 16 lanes sharing this row (masks < 16 stay in q-group)
            #pragma unroll
            for (int m = 1; m < 16; m <<= 1) {
                pe += __shfl_xor(pe, m);
                pc += __shfl_xor(pc, m);
            }
            if (ln == 0) {
                ws_pe[(size_t)row * 64 + cb] = pe;
                ws_pc[(size_t)row * 64 + cb] = pc;
            }
        }
    }
}

// ---------------------------------------------------------------------------
// Kernel 3: per-row finalize + global reduction into d_out[3].
// Wave-per-row: 128 blocks x 256 threads, 64 rows per block (16 rows/wave).
// ---------------------------------------------------------------------------
__global__ __launch_bounds__(256) void k_final(
    const float* __restrict__ ws_pe, const float* __restrict__ ws_pc,
    const float* __restrict__ pos_arr, float* __restrict__ out)
{
    int w = threadIdx.x >> 6, l = threadIdx.x & 63;
    float lsum = 0.f, a1sum = 0.f, a5sum = 0.f;
    #pragma unroll 4
    for (int j = 0; j < 16; ++j) {
        int row = blockIdx.x * 64 + j * 4 + w;
        float pe = ws_pe[(size_t)row * 64 + l];
        float pc = ws_pc[(size_t)row * 64 + l];
        for (int m = 1; m < 64; m <<= 1) {
            pe += __shfl_xor(pe, m);
            pc += __shfl_xor(pc, m);
        }
        if (l == 0) {
            float pos = pos_arr[row];
            lsum += logf(__expf(pos) + pe) - pos;   // logsumexp - pos (logits bounded)
            a1sum += (pc < 0.5f) ? 1.f : 0.f;       // no neg strictly > pos
            a5sum += (pc < 4.5f) ? 1.f : 0.f;       // at most 4 negs strictly > pos
        }
    }
    __shared__ float red[3][4];
    if (l == 0) { red[0][w] = lsum; red[1][w] = a1sum; red[2][w] = a5sum; }
    __syncthreads();
    if (threadIdx.x == 0) {
        float L = red[0][0] + red[0][1] + red[0][2] + red[0][3];
        float A1 = red[1][0] + red[1][1] + red[1][2] + red[1][3];
        float A5 = red[2][0] + red[2][1] + red[2][2] + red[2][3];
        atomicAdd(&out[0], L / (float)B_SZ);
        atomicAdd(&out[1], A1 * (100.f / (float)B_SZ));
        atomicAdd(&out[2], A5 * (100.f / (float)B_SZ));
    }
}

// ---------------------------------------------------------------------------
extern "C" void kernel_launch(void* const* d_in, const int* in_sizes, int n_in,
                              void* d_out, int out_size, void* d_ws, size_t ws_size,
                              hipStream_t stream)
{
    const float* zi = (const float*)d_in[0];
    const float* zj = (const float*)d_in[1];
    const int* perm = (const int*)d_in[2];
    float* out = (float*)d_out;

    // workspace layout (all 16B aligned)
    char* p = (char*)d_ws;
    unsigned short* A = (unsigned short*)p;  p += (size_t)B_SZ * D_SZ * 2;      // 8 MB
    unsigned short* G = (unsigned short*)p;  p += (size_t)2 * K_SZ * D_SZ * 2;  // 4 MB
    float* ni_arr = (float*)p;               p += (size_t)B_SZ * 4;
    float* pos_arr = (float*)p;              p += (size_t)B_SZ * 4;
    float* njc = (float*)p;                  p += (size_t)2 * K_SZ * 4;
    float* ws_pe = (float*)p;                p += (size_t)B_SZ * 64 * 4;        // 2 MB
    float* ws_pc = (float*)p;                p += (size_t)B_SZ * 64 * 4;        // 2 MB

    hipMemsetAsync(d_out, 0, 3 * sizeof(float), stream);

    k_prep<<<2048 + 1024, 256, 0, stream>>>(zi, zj, perm, ni_arr, pos_arr, A, njc, G);
    k_gemm<<<dim3(32, 64), 256, 0, stream>>>(A, G, perm, ni_arr, njc, pos_arr,
                                             ws_pe, ws_pc);
    k_final<<<128, 256, 0, stream>>>(ws_pe, ws_pc, pos_arr, out);
}

// Round 6
// 154.500 us; speedup vs baseline: 1.5495x; 1.5495x over previous
//
#include <hip/hip_runtime.h>
#include <cstdint>

#define B_SZ 8192
#define D_SZ 512
#define K_SZ 2048
#define EPSV 1e-8f
// 1/TEMP
#define INV_T 2.0f

typedef short short8 __attribute__((ext_vector_type(8)));
typedef float floatx4 __attribute__((ext_vector_type(4)));

// fp32 -> bf16 round-to-nearest-even (inputs are finite random normals; no NaN path)
__device__ __forceinline__ unsigned short f2bf(float f) {
    unsigned int u = __float_as_uint(f);
    u += 0x7FFFu + ((u >> 16) & 1u);
    return (unsigned short)(u >> 16);
}

// async global->LDS, 16B per lane. LDS dest must be wave-uniform base + lane*16.
__device__ __forceinline__ void async_cp16(const void* g, void* l) {
    typedef __attribute__((address_space(1))) unsigned int gds_t;
    typedef __attribute__((address_space(3))) unsigned int lds_t;
    __builtin_amdgcn_global_load_lds((gds_t*)(unsigned long long)g, (lds_t*)l, 16, 0, 0);
}

// ---------------------------------------------------------------------------
// Kernel 1 (merged prep+gather):
//  blocks [0,2048):  per-row norms of z_i/z_j, positive logit, z_i -> bf16 A
//  blocks [2048,3072): gather 2K=4096 rows (c_k, c_k+1) of z_j -> bf16 G + norms
// Stores RECIPROCAL scales (INV_T/ni, 1/nj) so the GEMM epilogue needs no
// rcp/max per element. One wave per row in both halves.
// ---------------------------------------------------------------------------
__global__ __launch_bounds__(256) void k_prep(
    const float* __restrict__ zi, const float* __restrict__ zj,
    const int* __restrict__ perm,
    float* __restrict__ ri_arr, float* __restrict__ pos_arr,
    unsigned short* __restrict__ A,
    float* __restrict__ rj_arr, unsigned short* __restrict__ G)
{
    int w = threadIdx.x >> 6, l = threadIdx.x & 63;
    if (blockIdx.x < 2048) {
        int row = blockIdx.x * 4 + w;
        const float4* zi4 = (const float4*)(zi + (size_t)row * D_SZ);
        const float4* zj4 = (const float4*)(zj + (size_t)row * D_SZ);
        float4 a0 = zi4[2 * l], a1 = zi4[2 * l + 1];
        float4 b0 = zj4[2 * l], b1 = zj4[2 * l + 1];
        float si = a0.x * a0.x + a0.y * a0.y + a0.z * a0.z + a0.w * a0.w
                 + a1.x * a1.x + a1.y * a1.y + a1.z * a1.z + a1.w * a1.w;
        float sj = b0.x * b0.x + b0.y * b0.y + b0.z * b0.z + b0.w * b0.w
                 + b1.x * b1.x + b1.y * b1.y + b1.z * b1.z + b1.w * b1.w;
        float dd = a0.x * b0.x + a0.y * b0.y + a0.z * b0.z + a0.w * b0.w
                 + a1.x * b1.x + a1.y * b1.y + a1.z * b1.z + a1.w * b1.w;
        for (int m = 1; m < 64; m <<= 1) {
            si += __shfl_xor(si, m);
            sj += __shfl_xor(sj, m);
            dd += __shfl_xor(dd, m);
        }
        if (l == 0) {
            float ni = sqrtf(si), nj = sqrtf(sj);
            ri_arr[row] = INV_T / fmaxf(ni, 1e-6f);   // norms ~22; eps never binds
            pos_arr[row] = dd / fmaxf(ni * nj, EPSV) * INV_T;
        }
        union { unsigned short u[8]; uint4 v; } pk;
        pk.u[0] = f2bf(a0.x); pk.u[1] = f2bf(a0.y); pk.u[2] = f2bf(a0.z); pk.u[3] = f2bf(a0.w);
        pk.u[4] = f2bf(a1.x); pk.u[5] = f2bf(a1.y); pk.u[6] = f2bf(a1.z); pk.u[7] = f2bf(a1.w);
        *(uint4*)(A + (size_t)row * D_SZ + l * 8) = pk.v;
    } else {
        int g = (blockIdx.x - 2048) * 4 + w;        // 0..4095
        int c = perm[g >> 1] + (g & 1);             // actual z_j row
        const float4* src = (const float4*)(zj + (size_t)c * D_SZ);
        float4 a0 = src[2 * l], a1 = src[2 * l + 1];
        float s = a0.x * a0.x + a0.y * a0.y + a0.z * a0.z + a0.w * a0.w
                + a1.x * a1.x + a1.y * a1.y + a1.z * a1.z + a1.w * a1.w;
        for (int m = 1; m < 64; m <<= 1) s += __shfl_xor(s, m);
        if (l == 0) rj_arr[g] = 1.0f / fmaxf(sqrtf(s), 1e-6f);
        union { unsigned short u[8]; uint4 v; } pk;
        pk.u[0] = f2bf(a0.x); pk.u[1] = f2bf(a0.y); pk.u[2] = f2bf(a0.z); pk.u[3] = f2bf(a0.w);
        pk.u[4] = f2bf(a1.x); pk.u[5] = f2bf(a1.y); pk.u[6] = f2bf(a1.z); pk.u[7] = f2bf(a1.w);
        *(uint4*)(G + (size_t)g * D_SZ + l * 8) = pk.v;
    }
}

// ---------------------------------------------------------------------------
// Kernel 2: bf16 MFMA GEMM S = A (8192x512) . G^T (512x4096), fused epilogue.
// 128x128 tile, BK=64, 256 threads (4 waves, 2x2), 16x16x32 MFMA.
// Double-buffered LDS (R2 skeleton: 2x(16+16) KB, 8-slot XOR swizzle,
// measured 0 bank conflicts).
// XCD-AWARE BLOCK MAPPING (bid -> XCD is bid&7 on MI355X): each XCD owns a
// fixed 512-column slab of G (512 KB -> L2-resident) and walks all 64 A
// row-panels in the same order as the other XCDs (LLC serves each A panel
// once to all 8 XCDs). Cuts per-XCD L2 miss traffic ~5x.
// ---------------------------------------------------------------------------
__global__ __launch_bounds__(256) void k_gemm(
    const unsigned short* __restrict__ A,   // [8192][512] bf16
    const unsigned short* __restrict__ G,   // [4096][512] bf16
    const int* __restrict__ perm,           // [2048]
    const float* __restrict__ ri_arr,       // [8192]  INV_T/ni
    const float* __restrict__ rj_arr,       // [4096]  1/nj
    const float* __restrict__ pos_arr,      // [8192]
    float* __restrict__ ws_pe, float* __restrict__ ws_pc)  // [8192][64]
{
    __shared__ unsigned short Asl[2][128 * 64];
    __shared__ unsigned short Gsl[2][128 * 64];
    const int tid = threadIdx.x;
    const int l = tid & 63, w = tid >> 6;
    const int wm = w >> 1, wn = w & 1;
    const int q = l >> 4, ln = l & 15;

    // XCD-aware tile mapping: 2048 blocks, xcd = bid&7 owns col-slab xcd*4..+4
    const int bid = blockIdx.x;
    const int xcd = bid & 7;
    const int slot = bid >> 3;              // 0..255
    const int colTile = xcd * 4 + (slot & 3);   // 0..31
    const int rowTile = slot >> 2;              // 0..63
    const int rowBase = rowTile * 128;
    const int colBase = colTile * 128;

    // per-thread staging offsets (elements); source advances 64 elems per dblk
    size_t aOff[4], gOff[4];
    int ldsOff[4];
    #pragma unroll
    for (int it = 0; it < 4; ++it) {
        int fc = it * 256 + tid;            // chunk 0..1023 (8 bf16 each)
        int r = fc >> 3;
        int scc = (fc & 7) ^ (r & 7);       // XOR swizzle source chunk
        aOff[it] = (size_t)(rowBase + r) * D_SZ + scc * 8;
        gOff[it] = (size_t)(colBase + r) * D_SZ + scc * 8;
        ldsOff[it] = fc * 8;
    }

    floatx4 acc[4][4] = {};

    // prologue: stage k-block 0 into buffer 0
    #pragma unroll
    for (int it = 0; it < 4; ++it) {
        async_cp16(A + aOff[it], &Asl[0][ldsOff[it]]);
        async_cp16(G + gOff[it], &Gsl[0][ldsOff[it]]);
    }

    #pragma unroll 1
    for (int dblk = 0; dblk < 8; ++dblk) {
        const int cur = dblk & 1, nxt = cur ^ 1;
        __syncthreads();                    // staged data for `cur` is ready
        if (dblk < 7) {
            #pragma unroll
            for (int it = 0; it < 4; ++it) {
                async_cp16(A + aOff[it] + (size_t)(dblk + 1) * 64, &Asl[nxt][ldsOff[it]]);
                async_cp16(G + gOff[it] + (size_t)(dblk + 1) * 64, &Gsl[nxt][ldsOff[it]]);
            }
        }
        #pragma unroll
        for (int kc = 0; kc < 2; ++kc) {
            short8 af[4], bfr[4];
            #pragma unroll
            for (int t = 0; t < 4; ++t) {
                int ar = wm * 64 + t * 16 + ln;
                int ac = (kc * 4 + q) ^ (ar & 7);
                af[t] = *(const short8*)&Asl[cur][ar * 64 + ac * 8];
                int br = wn * 64 + t * 16 + ln;
                int bc = (kc * 4 + q) ^ (br & 7);
                bfr[t] = *(const short8*)&Gsl[cur][br * 64 + bc * 8];
            }
            #pragma unroll
            for (int tm = 0; tm < 4; ++tm)
                #pragma unroll
                for (int tn = 0; tn < 4; ++tn)
                    acc[tm][tn] = __builtin_amdgcn_mfma_f32_16x16x32_bf16(
                        af[tm], bfr[tn], acc[tm][tn], 0, 0, 0);
        }
    }

    // ---- fused epilogue (slimmed: 2 muls + exp + 2 cmp/sel per element) ----
    // C/D layout: col = ln, row = q*4 + reg
    const int cb = colTile * 2 + wn;        // 64-col chunk index, 0..63
    float rjv[4]; int cv[4], shv[4];
    #pragma unroll
    for (int tn = 0; tn < 4; ++tn) {
        int g = colBase + wn * 64 + tn * 16 + ln;
        cv[tn] = perm[g >> 1];
        shv[tn] = g & 1;
        rjv[tn] = rj_arr[g];
    }
    #pragma unroll
    for (int tm = 0; tm < 4; ++tm) {
        int row0 = rowBase + wm * 64 + tm * 16 + q * 4;
        #pragma unroll
        for (int r = 0; r < 4; ++r) {
            int row = row0 + r;
            float riv = ri_arr[row];        // INV_T / ni
            float pv = pos_arr[row];
            float pe = 0.f, pc = 0.f;
            #pragma unroll
            for (int tn = 0; tn < 4; ++tn) {
                float logit = acc[tm][tn][r] * riv * rjv[tn];
                // row uses column c+1 iff c >= row; our gathered col is c+shv
                bool use = ((cv[tn] >= row) ? 1 : 0) == shv[tn];
                pe += use ? __expf(logit) : 0.f;
                pc += (use && logit > pv) ? 1.f : 0.f;
            }
            // reduce over the 16 lanes sharing this row (masks < 16 stay in q-group)
            #pragma unroll
            for (int m = 1; m < 16; m <<= 1) {
                pe += __shfl_xor(pe, m);
                pc += __shfl_xor(pc, m);
            }
            if (ln == 0) {
                ws_pe[(size_t)row * 64 + cb] = pe;
                ws_pc[(size_t)row * 64 + cb] = pc;
            }
        }
    }
}

// ---------------------------------------------------------------------------
// Kernel 3: per-row finalize + global reduction into d_out[3].
// Wave-per-row: 128 blocks x 256 threads, 64 rows per block (16 rows/wave).
// ---------------------------------------------------------------------------
__global__ __launch_bounds__(256) void k_final(
    const float* __restrict__ ws_pe, const float* __restrict__ ws_pc,
    const float* __restrict__ pos_arr, float* __restrict__ out)
{
    int w = threadIdx.x >> 6, l = threadIdx.x & 63;
    float lsum = 0.f, a1sum = 0.f, a5sum = 0.f;
    #pragma unroll 4
    for (int j = 0; j < 16; ++j) {
        int row = blockIdx.x * 64 + j * 4 + w;
        float pe = ws_pe[(size_t)row * 64 + l];
        float pc = ws_pc[(size_t)row * 64 + l];
        for (int m = 1; m < 64; m <<= 1) {
            pe += __shfl_xor(pe, m);
            pc += __shfl_xor(pc, m);
        }
        if (l == 0) {
            float pos = pos_arr[row];
            lsum += logf(__expf(pos) + pe) - pos;   // logsumexp - pos (logits bounded)
            a1sum += (pc < 0.5f) ? 1.f : 0.f;       // no neg strictly > pos
            a5sum += (pc < 4.5f) ? 1.f : 0.f;       // at most 4 negs strictly > pos
        }
    }
    __shared__ float red[3][4];
    if (l == 0) { red[0][w] = lsum; red[1][w] = a1sum; red[2][w] = a5sum; }
    __syncthreads();
    if (threadIdx.x == 0) {
        float L = red[0][0] + red[0][1] + red[0][2] + red[0][3];
        float A1 = red[1][0] + red[1][1] + red[1][2] + red[1][3];
        float A5 = red[2][0] + red[2][1] + red[2][2] + red[2][3];
        atomicAdd(&out[0], L / (float)B_SZ);
        atomicAdd(&out[1], A1 * (100.f / (float)B_SZ));
        atomicAdd(&out[2], A5 * (100.f / (float)B_SZ));
    }
}

// ---------------------------------------------------------------------------
extern "C" void kernel_launch(void* const* d_in, const int* in_sizes, int n_in,
                              void* d_out, int out_size, void* d_ws, size_t ws_size,
                              hipStream_t stream)
{
    const float* zi = (const float*)d_in[0];
    const float* zj = (const float*)d_in[1];
    const int* perm = (const int*)d_in[2];
    float* out = (float*)d_out;

    // workspace layout (all 16B aligned)
    char* p = (char*)d_ws;
    unsigned short* A = (unsigned short*)p;  p += (size_t)B_SZ * D_SZ * 2;      // 8 MB
    unsigned short* G = (unsigned short*)p;  p += (size_t)2 * K_SZ * D_SZ * 2;  // 4 MB
    float* ri_arr = (float*)p;               p += (size_t)B_SZ * 4;
    float* pos_arr = (float*)p;              p += (size_t)B_SZ * 4;
    float* rj_arr = (float*)p;               p += (size_t)2 * K_SZ * 4;
    float* ws_pe = (float*)p;                p += (size_t)B_SZ * 64 * 4;        // 2 MB
    float* ws_pc = (float*)p;                p += (size_t)B_SZ * 64 * 4;        // 2 MB

    hipMemsetAsync(d_out, 0, 3 * sizeof(float), stream);

    k_prep<<<2048 + 1024, 256, 0, stream>>>(zi, zj, perm, ri_arr, pos_arr, A, rj_arr, G);
    k_gemm<<<2048, 256, 0, stream>>>(A, G, perm, ri_arr, rj_arr, pos_arr,
                                     ws_pe, ws_pc);
    k_final<<<128, 256, 0, stream>>>(ws_pe, ws_pc, pos_arr, out);
}

// Round 7
// 144.580 us; speedup vs baseline: 1.6558x; 1.0686x over previous
//
#include <hip/hip_runtime.h>
#include <cstdint>

#define B_SZ 8192
#define D_SZ 512
#define K_SZ 2048
#define EPSV 1e-8f
// 1/TEMP
#define INV_T 2.0f

typedef float floatx4 __attribute__((ext_vector_type(4)));

// async global->LDS, 16B per lane. LDS dest must be wave-uniform base + lane*16.
__device__ __forceinline__ void async_cp16(const void* g, void* l) {
    typedef __attribute__((address_space(1))) unsigned int gds_t;
    typedef __attribute__((address_space(3))) unsigned int lds_t;
    __builtin_amdgcn_global_load_lds((gds_t*)(unsigned long long)g, (lds_t*)l, 16, 0, 0);
}

// pack 8 fp32 -> 8 fp8 e4m3 (OCP, RNE, saturating) as int2
__device__ __forceinline__ int2 pack_fp8x8(float4 a0, float4 a1) {
    int w0 = __builtin_amdgcn_cvt_pk_fp8_f32(a0.x, a0.y, 0, false);
    w0 = __builtin_amdgcn_cvt_pk_fp8_f32(a0.z, a0.w, w0, true);
    int w1 = __builtin_amdgcn_cvt_pk_fp8_f32(a1.x, a1.y, 0, false);
    w1 = __builtin_amdgcn_cvt_pk_fp8_f32(a1.z, a1.w, w1, true);
    return make_int2(w0, w1);
}

// ---------------------------------------------------------------------------
// Kernel 1 (merged prep+gather):
//  blocks [0,2048):  per-row norms of z_i/z_j, positive logit, z_i -> fp8 A
//  blocks [2048,3072): gather 2K=4096 rows (c_k, c_k+1) of z_j -> fp8 G + norms
// Stores RECIPROCAL scales (INV_T/ni, 1/nj). pos logit computed in full fp32.
// ---------------------------------------------------------------------------
__global__ __launch_bounds__(256) void k_prep(
    const float* __restrict__ zi, const float* __restrict__ zj,
    const int* __restrict__ perm,
    float* __restrict__ ri_arr, float* __restrict__ pos_arr,
    unsigned char* __restrict__ A,
    float* __restrict__ rj_arr, unsigned char* __restrict__ G)
{
    int w = threadIdx.x >> 6, l = threadIdx.x & 63;
    if (blockIdx.x < 2048) {
        int row = blockIdx.x * 4 + w;
        const float4* zi4 = (const float4*)(zi + (size_t)row * D_SZ);
        const float4* zj4 = (const float4*)(zj + (size_t)row * D_SZ);
        float4 a0 = zi4[2 * l], a1 = zi4[2 * l + 1];
        float4 b0 = zj4[2 * l], b1 = zj4[2 * l + 1];
        float si = a0.x * a0.x + a0.y * a0.y + a0.z * a0.z + a0.w * a0.w
                 + a1.x * a1.x + a1.y * a1.y + a1.z * a1.z + a1.w * a1.w;
        float sj = b0.x * b0.x + b0.y * b0.y + b0.z * b0.z + b0.w * b0.w
                 + b1.x * b1.x + b1.y * b1.y + b1.z * b1.z + b1.w * b1.w;
        float dd = a0.x * b0.x + a0.y * b0.y + a0.z * b0.z + a0.w * b0.w
                 + a1.x * b1.x + a1.y * b1.y + a1.z * b1.z + a1.w * b1.w;
        for (int m = 1; m < 64; m <<= 1) {
            si += __shfl_xor(si, m);
            sj += __shfl_xor(sj, m);
            dd += __shfl_xor(dd, m);
        }
        if (l == 0) {
            float ni = sqrtf(si), nj = sqrtf(sj);
            ri_arr[row] = INV_T / fmaxf(ni, 1e-6f);   // norms ~22; eps never binds
            pos_arr[row] = dd / fmaxf(ni * nj, EPSV) * INV_T;
        }
        *(int2*)(A + (size_t)row * D_SZ + l * 8) = pack_fp8x8(a0, a1);
    } else {
        int g = (blockIdx.x - 2048) * 4 + w;        // 0..4095
        int c = perm[g >> 1] + (g & 1);             // actual z_j row
        const float4* src = (const float4*)(zj + (size_t)c * D_SZ);
        float4 a0 = src[2 * l], a1 = src[2 * l + 1];
        float s = a0.x * a0.x + a0.y * a0.y + a0.z * a0.z + a0.w * a0.w
                + a1.x * a1.x + a1.y * a1.y + a1.z * a1.z + a1.w * a1.w;
        for (int m = 1; m < 64; m <<= 1) s += __shfl_xor(s, m);
        if (l == 0) rj_arr[g] = 1.0f / fmaxf(sqrtf(s), 1e-6f);
        *(int2*)(G + (size_t)g * D_SZ + l * 8) = pack_fp8x8(a0, a1);
    }
}

// ---------------------------------------------------------------------------
// Kernel 2: fp8 MFMA GEMM S = A (8192x512) . G^T (512x4096), fused epilogue.
// 128x128 tile, BK=64, 256 threads (4 waves, 2x2), 16x16x32_fp8_fp8 MFMA
// (bf16 rate, half the bytes). Double-buffered LDS: 2 x (8+8) KB = 32 KB.
// 16B-chunk XOR swizzle (slot = c16 ^ (row&3)); the b64 frag read then has
// the exact bank profile of a linear stride-1 b64 wave read -> conflict-free.
// XCD-aware mapping (bid&7 = XCD owns a 512-col G slab, L2-resident; all
// XCDs walk A row-panels in lockstep so LLC serves each panel once).
// ---------------------------------------------------------------------------
__global__ __launch_bounds__(256, 3) void k_gemm(
    const unsigned char* __restrict__ A,    // [8192][512] fp8
    const unsigned char* __restrict__ G,    // [4096][512] fp8
    const int* __restrict__ perm,           // [2048]
    const float* __restrict__ ri_arr,       // [8192]  INV_T/ni
    const float* __restrict__ rj_arr,       // [4096]  1/nj
    const float* __restrict__ pos_arr,      // [8192]
    float* __restrict__ ws_pe, float* __restrict__ ws_pc)  // [8192][64]
{
    __shared__ unsigned char Asl[2][128 * 64];   // 8 KB per buffer
    __shared__ unsigned char Gsl[2][128 * 64];
    const int tid = threadIdx.x;
    const int l = tid & 63, w = tid >> 6;
    const int wm = w >> 1, wn = w & 1;
    const int q = l >> 4, ln = l & 15;

    // XCD-aware tile mapping: 2048 blocks, xcd = bid&7 owns col-slab xcd*4..+4
    const int bid = blockIdx.x;
    const int xcd = bid & 7;
    const int slot = bid >> 3;              // 0..255
    const int colTile = xcd * 4 + (slot & 3);   // 0..31
    const int rowTile = slot >> 2;              // 0..63
    const int rowBase = rowTile * 128;
    const int colBase = colTile * 128;

    // staging offsets (bytes); 512 16B-chunks per array per dblk (2 iters x 256)
    size_t aOff[2], gOff[2];
    int ldsOff[2];
    #pragma unroll
    for (int it = 0; it < 2; ++it) {
        int fc = it * 256 + tid;            // 16B chunk 0..511
        int r = fc >> 2, s = fc & 3;
        int scc = s ^ (r & 3);              // XOR swizzle source 16B chunk
        aOff[it] = (size_t)(rowBase + r) * D_SZ + scc * 16;
        gOff[it] = (size_t)(colBase + r) * D_SZ + scc * 16;
        ldsOff[it] = fc * 16;
    }

    floatx4 acc[4][4] = {};

    // prologue: stage k-block 0 into buffer 0
    #pragma unroll
    for (int it = 0; it < 2; ++it) {
        async_cp16(A + aOff[it], &Asl[0][ldsOff[it]]);
        async_cp16(G + gOff[it], &Gsl[0][ldsOff[it]]);
    }

    #pragma unroll 1
    for (int dblk = 0; dblk < 8; ++dblk) {
        const int cur = dblk & 1, nxt = cur ^ 1;
        __syncthreads();                    // staged data for `cur` is ready
        if (dblk < 7) {
            #pragma unroll
            for (int it = 0; it < 2; ++it) {
                async_cp16(A + aOff[it] + (size_t)(dblk + 1) * 64, &Asl[nxt][ldsOff[it]]);
                async_cp16(G + gOff[it] + (size_t)(dblk + 1) * 64, &Gsl[nxt][ldsOff[it]]);
            }
        }
        #pragma unroll
        for (int kc = 0; kc < 2; ++kc) {
            long af[4], bfr[4];
            #pragma unroll
            for (int t = 0; t < 4; ++t) {
                int ar = wm * 64 + t * 16 + ln;
                int aa = ar * 64 + (((kc * 2 + (q >> 1)) ^ (ar & 3)) * 16) + (q & 1) * 8;
                af[t] = *(const long*)&Asl[cur][aa];
                int br = wn * 64 + t * 16 + ln;
                int ba = br * 64 + (((kc * 2 + (q >> 1)) ^ (br & 3)) * 16) + (q & 1) * 8;
                bfr[t] = *(const long*)&Gsl[cur][ba];
            }
            #pragma unroll
            for (int tm = 0; tm < 4; ++tm)
                #pragma unroll
                for (int tn = 0; tn < 4; ++tn)
                    acc[tm][tn] = __builtin_amdgcn_mfma_f32_16x16x32_fp8_fp8(
                        af[tm], bfr[tn], acc[tm][tn], 0, 0, 0);
        }
    }

    // ---- fused epilogue (2 muls + exp + 2 cmp/sel per element) ----
    // C/D layout: col = ln, row = q*4 + reg (shape-determined, dtype-indep)
    const int cb = colTile * 2 + wn;        // 64-col chunk index, 0..63
    float rjv[4]; int cv[4], shv[4];
    #pragma unroll
    for (int tn = 0; tn < 4; ++tn) {
        int g = colBase + wn * 64 + tn * 16 + ln;
        cv[tn] = perm[g >> 1];
        shv[tn] = g & 1;
        rjv[tn] = rj_arr[g];
    }
    #pragma unroll
    for (int tm = 0; tm < 4; ++tm) {
        int row0 = rowBase + wm * 64 + tm * 16 + q * 4;
        #pragma unroll
        for (int r = 0; r < 4; ++r) {
            int row = row0 + r;
            float riv = ri_arr[row];        // INV_T / ni
            float pv = pos_arr[row];
            float pe = 0.f, pc = 0.f;
            #pragma unroll
            for (int tn = 0; tn < 4; ++tn) {
                float logit = acc[tm][tn][r] * riv * rjv[tn];
                // row uses column c+1 iff c >= row; our gathered col is c+shv
                bool use = ((cv[tn] >= row) ? 1 : 0) == shv[tn];
                pe += use ? __expf(logit) : 0.f;
                pc += (use && logit > pv) ? 1.f : 0.f;
            }
            // reduce over the 16 lanes sharing this row (masks < 16 stay in q-group)
            #pragma unroll
            for (int m = 1; m < 16; m <<= 1) {
                pe += __shfl_xor(pe, m);
                pc += __shfl_xor(pc, m);
            }
            if (ln == 0) {
                ws_pe[(size_t)row * 64 + cb] = pe;
                ws_pc[(size_t)row * 64 + cb] = pc;
            }
        }
    }
}

// ---------------------------------------------------------------------------
// Kernel 3: per-row finalize + global reduction into d_out[3].
// Wave-per-row: 128 blocks x 256 threads, 64 rows per block (16 rows/wave).
// ---------------------------------------------------------------------------
__global__ __launch_bounds__(256) void k_final(
    const float* __restrict__ ws_pe, const float* __restrict__ ws_pc,
    const float* __restrict__ pos_arr, float* __restrict__ out)
{
    int w = threadIdx.x >> 6, l = threadIdx.x & 63;
    float lsum = 0.f, a1sum = 0.f, a5sum = 0.f;
    #pragma unroll 4
    for (int j = 0; j < 16; ++j) {
        int row = blockIdx.x * 64 + j * 4 + w;
        float pe = ws_pe[(size_t)row * 64 + l];
        float pc = ws_pc[(size_t)row * 64 + l];
        for (int m = 1; m < 64; m <<= 1) {
            pe += __shfl_xor(pe, m);
            pc += __shfl_xor(pc, m);
        }
        if (l == 0) {
            float pos = pos_arr[row];
            lsum += logf(__expf(pos) + pe) - pos;   // logsumexp - pos (logits bounded)
            a1sum += (pc < 0.5f) ? 1.f : 0.f;       // no neg strictly > pos
            a5sum += (pc < 4.5f) ? 1.f : 0.f;       // at most 4 negs strictly > pos
        }
    }
    __shared__ float red[3][4];
    if (l == 0) { red[0][w] = lsum; red[1][w] = a1sum; red[2][w] = a5sum; }
    __syncthreads();
    if (threadIdx.x == 0) {
        float L = red[0][0] + red[0][1] + red[0][2] + red[0][3];
        float A1 = red[1][0] + red[1][1] + red[1][2] + red[1][3];
        float A5 = red[2][0] + red[2][1] + red[2][2] + red[2][3];
        atomicAdd(&out[0], L / (float)B_SZ);
        atomicAdd(&out[1], A1 * (100.f / (float)B_SZ));
        atomicAdd(&out[2], A5 * (100.f / (float)B_SZ));
    }
}

// ---------------------------------------------------------------------------
extern "C" void kernel_launch(void* const* d_in, const int* in_sizes, int n_in,
                              void* d_out, int out_size, void* d_ws, size_t ws_size,
                              hipStream_t stream)
{
    const float* zi = (const float*)d_in[0];
    const float* zj = (const float*)d_in[1];
    const int* perm = (const int*)d_in[2];
    float* out = (float*)d_out;

    // workspace layout (all 16B aligned)
    char* p = (char*)d_ws;
    unsigned char* A = (unsigned char*)p;    p += (size_t)B_SZ * D_SZ;          // 4 MB
    unsigned char* G = (unsigned char*)p;    p += (size_t)2 * K_SZ * D_SZ;      // 2 MB
    float* ri_arr = (float*)p;               p += (size_t)B_SZ * 4;
    float* pos_arr = (float*)p;              p += (size_t)B_SZ * 4;
    float* rj_arr = (float*)p;               p += (size_t)2 * K_SZ * 4;
    float* ws_pe = (float*)p;                p += (size_t)B_SZ * 64 * 4;        // 2 MB
    float* ws_pc = (float*)p;                p += (size_t)B_SZ * 64 * 4;        // 2 MB

    hipMemsetAsync(d_out, 0, 3 * sizeof(float), stream);

    k_prep<<<2048 + 1024, 256, 0, stream>>>(zi, zj, perm, ri_arr, pos_arr, A, rj_arr, G);
    k_gemm<<<2048, 256, 0, stream>>>(A, G, perm, ri_arr, rj_arr, pos_arr,
                                     ws_pe, ws_pc);
    k_final<<<128, 256, 0, stream>>>(ws_pe, ws_pc, pos_arr, out);
}

// Round 8
// 141.164 us; speedup vs baseline: 1.6958x; 1.0242x over previous
//
#include <hip/hip_runtime.h>
#include <cstdint>

#define B_SZ 8192
#define D_SZ 512
#define K_SZ 2048
#define EPSV 1e-8f
// 1/TEMP
#define INV_T 2.0f

typedef float floatx16 __attribute__((ext_vector_type(16)));
typedef int intx8 __attribute__((ext_vector_type(8)));

// async global->LDS, 16B per lane. LDS dest must be wave-uniform base + lane*16.
__device__ __forceinline__ void async_cp16(const void* g, void* l) {
    typedef __attribute__((address_space(1))) unsigned int gds_t;
    typedef __attribute__((address_space(3))) unsigned int lds_t;
    __builtin_amdgcn_global_load_lds((gds_t*)(unsigned long long)g, (lds_t*)l, 16, 0, 0);
}

// pack 8 fp32 -> 8 fp8 e4m3 (OCP, RNE, saturating) as int2
__device__ __forceinline__ int2 pack_fp8x8(float4 a0, float4 a1) {
    int w0 = __builtin_amdgcn_cvt_pk_fp8_f32(a0.x, a0.y, 0, false);
    w0 = __builtin_amdgcn_cvt_pk_fp8_f32(a0.z, a0.w, w0, true);
    int w1 = __builtin_amdgcn_cvt_pk_fp8_f32(a1.x, a1.y, 0, false);
    w1 = __builtin_amdgcn_cvt_pk_fp8_f32(a1.z, a1.w, w1, true);
    return make_int2(w0, w1);
}

// ---------------------------------------------------------------------------
// Kernel 1 (merged prep+gather):
//  blocks [0,2048):  per-row norms of z_i/z_j, positive logit, z_i -> fp8 A
//  blocks [2048,3072): gather 2K=4096 rows (c_k, c_k+1) of z_j -> fp8 G + norms
// Stores RECIPROCAL scales (INV_T/ni, 1/nj). pos logit computed in full fp32.
// ---------------------------------------------------------------------------
__global__ __launch_bounds__(256) void k_prep(
    const float* __restrict__ zi, const float* __restrict__ zj,
    const int* __restrict__ perm,
    float* __restrict__ ri_arr, float* __restrict__ pos_arr,
    unsigned char* __restrict__ A,
    float* __restrict__ rj_arr, unsigned char* __restrict__ G)
{
    int w = threadIdx.x >> 6, l = threadIdx.x & 63;
    if (blockIdx.x < 2048) {
        int row = blockIdx.x * 4 + w;
        const float4* zi4 = (const float4*)(zi + (size_t)row * D_SZ);
        const float4* zj4 = (const float4*)(zj + (size_t)row * D_SZ);
        float4 a0 = zi4[2 * l], a1 = zi4[2 * l + 1];
        float4 b0 = zj4[2 * l], b1 = zj4[2 * l + 1];
        float si = a0.x * a0.x + a0.y * a0.y + a0.z * a0.z + a0.w * a0.w
                 + a1.x * a1.x + a1.y * a1.y + a1.z * a1.z + a1.w * a1.w;
        float sj = b0.x * b0.x + b0.y * b0.y + b0.z * b0.z + b0.w * b0.w
                 + b1.x * b1.x + b1.y * b1.y + b1.z * b1.z + b1.w * b1.w;
        float dd = a0.x * b0.x + a0.y * b0.y + a0.z * b0.z + a0.w * b0.w
                 + a1.x * b1.x + a1.y * b1.y + a1.z * b1.z + a1.w * b1.w;
        for (int m = 1; m < 64; m <<= 1) {
            si += __shfl_xor(si, m);
            sj += __shfl_xor(sj, m);
            dd += __shfl_xor(dd, m);
        }
        if (l == 0) {
            float ni = sqrtf(si), nj = sqrtf(sj);
            ri_arr[row] = INV_T / fmaxf(ni, 1e-6f);   // norms ~22; eps never binds
            pos_arr[row] = dd / fmaxf(ni * nj, EPSV) * INV_T;
        }
        *(int2*)(A + (size_t)row * D_SZ + l * 8) = pack_fp8x8(a0, a1);
    } else {
        int g = (blockIdx.x - 2048) * 4 + w;        // 0..4095
        int c = perm[g >> 1] + (g & 1);             // actual z_j row
        const float4* src = (const float4*)(zj + (size_t)c * D_SZ);
        float4 a0 = src[2 * l], a1 = src[2 * l + 1];
        float s = a0.x * a0.x + a0.y * a0.y + a0.z * a0.z + a0.w * a0.w
                + a1.x * a1.x + a1.y * a1.y + a1.z * a1.z + a1.w * a1.w;
        for (int m = 1; m < 64; m <<= 1) s += __shfl_xor(s, m);
        if (l == 0) rj_arr[g] = 1.0f / fmaxf(sqrtf(s), 1e-6f);
        *(int2*)(G + (size_t)g * D_SZ + l * 8) = pack_fp8x8(a0, a1);
    }
}

// ---------------------------------------------------------------------------
// Kernel 2: MX-fp8 MFMA GEMM S = A (8192x512) . G^T (512x4096), fused epilogue.
// v_mfma_scale_f32_32x32x64_f8f6f4 with unit scales (E8M0 0x7f = 2^0):
// numerically identical to plain e4m3, 2x the MFMA rate, and each lane's
// fragment is 32 B = TWO FULL 16B LDS chunks -> ds_read_b128 with the
// proven zero-conflict geometry.
// 128x128 tile, BK=64, 256 threads (2x2 waves of 64x64, each wave 2x2 MFMA
// tiles of 32x32). Double-buffered LDS 2 x (8+8) KB = 32 KB.
// Swizzle: LDS chunk (r, c) at slot c ^ ((r ^ (r>>2)) & 3): every 8
// consecutive lanes of a b128 read hit 8 distinct bank-quads -> 0 conflicts.
// XCD-aware mapping (bid&7 = XCD owns a 512-col G slab, L2-resident).
// ---------------------------------------------------------------------------
__global__ __launch_bounds__(256, 3) void k_gemm(
    const unsigned char* __restrict__ A,    // [8192][512] fp8
    const unsigned char* __restrict__ G,    // [4096][512] fp8
    const int* __restrict__ perm,           // [2048]
    const float* __restrict__ ri_arr,       // [8192]  INV_T/ni
    const float* __restrict__ rj_arr,       // [4096]  1/nj
    const float* __restrict__ pos_arr,      // [8192]
    float* __restrict__ ws_pe, float* __restrict__ ws_pc)  // [8192][64]
{
    __shared__ unsigned char Asl[2][128 * 64];   // 8 KB per buffer
    __shared__ unsigned char Gsl[2][128 * 64];
    const int tid = threadIdx.x;
    const int l = tid & 63, w = tid >> 6;
    const int wm = w >> 1, wn = w & 1;
    const int ln = l & 31, q = l >> 5;      // 32x32 MFMA lane decomposition

    // XCD-aware tile mapping: 2048 blocks, xcd = bid&7 owns col-slab xcd*4..+4
    const int bid = blockIdx.x;
    const int xcd = bid & 7;
    const int slot = bid >> 3;              // 0..255
    const int colTile = xcd * 4 + (slot & 3);   // 0..31
    const int rowTile = slot >> 2;              // 0..63
    const int rowBase = rowTile * 128;
    const int colBase = colTile * 128;

    // staging offsets (bytes); 512 16B-chunks per array per dblk (2 iters x 256)
    size_t aOff[2], gOff[2];
    int ldsOff[2];
    #pragma unroll
    for (int it = 0; it < 2; ++it) {
        int fc = it * 256 + tid;            // 16B chunk 0..511
        int r = fc >> 2, s = fc & 3;
        int scc = s ^ ((r ^ (r >> 2)) & 3); // XOR swizzle source 16B chunk
        aOff[it] = (size_t)(rowBase + r) * D_SZ + scc * 16;
        gOff[it] = (size_t)(colBase + r) * D_SZ + scc * 16;
        ldsOff[it] = fc * 16;
    }

    floatx16 acc[2][2] = {};

    // frag read addresses (bytes within an 8 KB buffer): lane needs k bytes
    // [q*32, q*32+32) of its row = pre-swizzle chunks {2q, 2q+1}
    int aAddr[2][2], gAddr[2][2];           // [t][chunk half]
    #pragma unroll
    for (int t = 0; t < 2; ++t) {
        int ar = wm * 64 + t * 32 + ln;
        int xa = (ar ^ (ar >> 2)) & 3;
        aAddr[t][0] = ar * 64 + ((2 * q) ^ xa) * 16;
        aAddr[t][1] = ar * 64 + ((2 * q + 1) ^ xa) * 16;
        int br = wn * 64 + t * 32 + ln;
        int xb = (br ^ (br >> 2)) & 3;
        gAddr[t][0] = br * 64 + ((2 * q) ^ xb) * 16;
        gAddr[t][1] = br * 64 + ((2 * q + 1) ^ xb) * 16;
    }

    // prologue: stage k-block 0 into buffer 0
    #pragma unroll
    for (int it = 0; it < 2; ++it) {
        async_cp16(A + aOff[it], &Asl[0][ldsOff[it]]);
        async_cp16(G + gOff[it], &Gsl[0][ldsOff[it]]);
    }

    #pragma unroll 1
    for (int dblk = 0; dblk < 8; ++dblk) {
        const int cur = dblk & 1, nxt = cur ^ 1;
        __syncthreads();                    // staged data for `cur` is ready
        if (dblk < 7) {
            #pragma unroll
            for (int it = 0; it < 2; ++it) {
                async_cp16(A + aOff[it] + (size_t)(dblk + 1) * 64, &Asl[nxt][ldsOff[it]]);
                async_cp16(G + gOff[it] + (size_t)(dblk + 1) * 64, &Gsl[nxt][ldsOff[it]]);
            }
        }
        intx8 af[2], gf[2];
        #pragma unroll
        for (int t = 0; t < 2; ++t) {
            int4 lo = *(const int4*)&Asl[cur][aAddr[t][0]];
            int4 hi = *(const int4*)&Asl[cur][aAddr[t][1]];
            af[t][0] = lo.x; af[t][1] = lo.y; af[t][2] = lo.z; af[t][3] = lo.w;
            af[t][4] = hi.x; af[t][5] = hi.y; af[t][6] = hi.z; af[t][7] = hi.w;
            int4 glo = *(const int4*)&Gsl[cur][gAddr[t][0]];
            int4 ghi = *(const int4*)&Gsl[cur][gAddr[t][1]];
            gf[t][0] = glo.x; gf[t][1] = glo.y; gf[t][2] = glo.z; gf[t][3] = glo.w;
            gf[t][4] = ghi.x; gf[t][5] = ghi.y; gf[t][6] = ghi.z; gf[t][7] = ghi.w;
        }
        #pragma unroll
        for (int tm = 0; tm < 2; ++tm)
            #pragma unroll
            for (int tn = 0; tn < 2; ++tn)
                acc[tm][tn] = __builtin_amdgcn_mfma_scale_f32_32x32x64_f8f6f4(
                    af[tm], gf[tn], acc[tm][tn],
                    0, 0,                       // cbsz = fp8 e4m3, blgp = fp8 e4m3
                    0, 0x7f7f7f7f,              // scale A: all-ones (2^0)
                    0, 0x7f7f7f7f);             // scale B: all-ones (2^0)
    }

    // ---- fused epilogue ----
    // 32x32 C/D layout: col = ln, row = (reg&3) + 8*(reg>>2) + 4*q
    const int cb = colTile * 2 + wn;        // 64-col chunk index, 0..63
    float rjv[2]; int cv[2], shv[2];
    #pragma unroll
    for (int tn = 0; tn < 2; ++tn) {
        int g = colBase + wn * 64 + tn * 32 + ln;
        cv[tn] = perm[g >> 1];
        shv[tn] = g & 1;
        rjv[tn] = rj_arr[g];
    }
    #pragma unroll
    for (int tm = 0; tm < 2; ++tm) {
        #pragma unroll
        for (int reg = 0; reg < 16; ++reg) {
            int row = rowBase + wm * 64 + tm * 32 + (reg & 3) + 8 * (reg >> 2) + 4 * q;
            float riv = ri_arr[row];        // INV_T / ni
            float pv = pos_arr[row];
            float pe = 0.f, pc = 0.f;
            #pragma unroll
            for (int tn = 0; tn < 2; ++tn) {
                float logit = acc[tm][tn][reg] * riv * rjv[tn];
                // row uses column c+1 iff c >= row; our gathered col is c+shv
                bool use = ((cv[tn] >= row) ? 1 : 0) == shv[tn];
                pe += use ? __expf(logit) : 0.f;
                pc += (use && logit > pv) ? 1.f : 0.f;
            }
            // reduce over the 32 lanes sharing this row (xor masks < 32 stay
            // within the q-half)
            #pragma unroll
            for (int m = 1; m < 32; m <<= 1) {
                pe += __shfl_xor(pe, m);
                pc += __shfl_xor(pc, m);
            }
            if (ln == 0) {
                ws_pe[(size_t)row * 64 + cb] = pe;
                ws_pc[(size_t)row * 64 + cb] = pc;
            }
        }
    }
}

// ---------------------------------------------------------------------------
// Kernel 3: per-row finalize + global reduction into d_out[3].
// Wave-per-row: 128 blocks x 256 threads, 64 rows per block (16 rows/wave).
// ---------------------------------------------------------------------------
__global__ __launch_bounds__(256) void k_final(
    const float* __restrict__ ws_pe, const float* __restrict__ ws_pc,
    const float* __restrict__ pos_arr, float* __restrict__ out)
{
    int w = threadIdx.x >> 6, l = threadIdx.x & 63;
    float lsum = 0.f, a1sum = 0.f, a5sum = 0.f;
    #pragma unroll 4
    for (int j = 0; j < 16; ++j) {
        int row = blockIdx.x * 64 + j * 4 + w;
        float pe = ws_pe[(size_t)row * 64 + l];
        float pc = ws_pc[(size_t)row * 64 + l];
        for (int m = 1; m < 64; m <<= 1) {
            pe += __shfl_xor(pe, m);
            pc += __shfl_xor(pc, m);
        }
        if (l == 0) {
            float pos = pos_arr[row];
            lsum += logf(__expf(pos) + pe) - pos;   // logsumexp - pos (logits bounded)
            a1sum += (pc < 0.5f) ? 1.f : 0.f;       // no neg strictly > pos
            a5sum += (pc < 4.5f) ? 1.f : 0.f;       // at most 4 negs strictly > pos
        }
    }
    __shared__ float red[3][4];
    if (l == 0) { red[0][w] = lsum; red[1][w] = a1sum; red[2][w] = a5sum; }
    __syncthreads();
    if (threadIdx.x == 0) {
        float L = red[0][0] + red[0][1] + red[0][2] + red[0][3];
        float A1 = red[1][0] + red[1][1] + red[1][2] + red[1][3];
        float A5 = red[2][0] + red[2][1] + red[2][2] + red[2][3];
        atomicAdd(&out[0], L / (float)B_SZ);
        atomicAdd(&out[1], A1 * (100.f / (float)B_SZ));
        atomicAdd(&out[2], A5 * (100.f / (float)B_SZ));
    }
}

// ---------------------------------------------------------------------------
extern "C" void kernel_launch(void* const* d_in, const int* in_sizes, int n_in,
                              void* d_out, int out_size, void* d_ws, size_t ws_size,
                              hipStream_t stream)
{
    const float* zi = (const float*)d_in[0];
    const float* zj = (const float*)d_in[1];
    const int* perm = (const int*)d_in[2];
    float* out = (float*)d_out;

    // workspace layout (all 16B aligned)
    char* p = (char*)d_ws;
    unsigned char* A = (unsigned char*)p;    p += (size_t)B_SZ * D_SZ;          // 4 MB
    unsigned char* G = (unsigned char*)p;    p += (size_t)2 * K_SZ * D_SZ;      // 2 MB
    float* ri_arr = (float*)p;               p += (size_t)B_SZ * 4;
    float* pos_arr = (float*)p;              p += (size_t)B_SZ * 4;
    float* rj_arr = (float*)p;               p += (size_t)2 * K_SZ * 4;
    float* ws_pe = (float*)p;                p += (size_t)B_SZ * 64 * 4;        // 2 MB
    float* ws_pc = (float*)p;                p += (size_t)B_SZ * 64 * 4;        // 2 MB

    hipMemsetAsync(d_out, 0, 3 * sizeof(float), stream);

    k_prep<<<2048 + 1024, 256, 0, stream>>>(zi, zj, perm, ri_arr, pos_arr, A, rj_arr, G);
    k_gemm<<<2048, 256, 0, stream>>>(A, G, perm, ri_arr, rj_arr, pos_arr,
                                     ws_pe, ws_pc);
    k_final<<<128, 256, 0, stream>>>(ws_pe, ws_pc, pos_arr, out);
}

// Round 9
// 125.358 us; speedup vs baseline: 1.9097x; 1.1261x over previous
//
#include <hip/hip_runtime.h>
#include <cstdint>

#define B_SZ 8192
#define D_SZ 512
#define K_SZ 2048
#define EPSV 1e-8f
// 1/TEMP
#define INV_T 2.0f

typedef float floatx16 __attribute__((ext_vector_type(16)));
typedef int intx8 __attribute__((ext_vector_type(8)));

// async global->LDS, 16B per lane. LDS dest must be wave-uniform base + lane*16.
__device__ __forceinline__ void async_cp16(const void* g, void* l) {
    typedef __attribute__((address_space(1))) unsigned int gds_t;
    typedef __attribute__((address_space(3))) unsigned int lds_t;
    __builtin_amdgcn_global_load_lds((gds_t*)(unsigned long long)g, (lds_t*)l, 16, 0, 0);
}

// pack 8 fp32 -> 8 fp8 e4m3 (OCP, RNE, saturating) as int2
__device__ __forceinline__ int2 pack_fp8x8(float4 a0, float4 a1) {
    int w0 = __builtin_amdgcn_cvt_pk_fp8_f32(a0.x, a0.y, 0, false);
    w0 = __builtin_amdgcn_cvt_pk_fp8_f32(a0.z, a0.w, w0, true);
    int w1 = __builtin_amdgcn_cvt_pk_fp8_f32(a1.x, a1.y, 0, false);
    w1 = __builtin_amdgcn_cvt_pk_fp8_f32(a1.z, a1.w, w1, true);
    return make_int2(w0, w1);
}

// ---------------------------------------------------------------------------
// Kernel 1 (merged prep+gather):
//  blocks [0,2048):  per-row norms of z_i/z_j, positive logit, z_i -> fp8 A
//  blocks [2048,3072): gather 2K=4096 rows (c_k, c_k+1) of z_j -> fp8 G,
//    plus per-g metadata gmeta[g] = {1/nj, bitcast(perm[g>>1])}.
// Stores RECIPROCAL scales. pos logit computed in full fp32.
// ---------------------------------------------------------------------------
__global__ __launch_bounds__(256) void k_prep(
    const float* __restrict__ zi, const float* __restrict__ zj,
    const int* __restrict__ perm,
    float* __restrict__ ri_arr, float* __restrict__ pos_arr,
    unsigned char* __restrict__ A,
    float2* __restrict__ gmeta, unsigned char* __restrict__ G)
{
    int w = threadIdx.x >> 6, l = threadIdx.x & 63;
    if (blockIdx.x < 2048) {
        int row = blockIdx.x * 4 + w;
        const float4* zi4 = (const float4*)(zi + (size_t)row * D_SZ);
        const float4* zj4 = (const float4*)(zj + (size_t)row * D_SZ);
        float4 a0 = zi4[2 * l], a1 = zi4[2 * l + 1];
        float4 b0 = zj4[2 * l], b1 = zj4[2 * l + 1];
        float si = a0.x * a0.x + a0.y * a0.y + a0.z * a0.z + a0.w * a0.w
                 + a1.x * a1.x + a1.y * a1.y + a1.z * a1.z + a1.w * a1.w;
        float sj = b0.x * b0.x + b0.y * b0.y + b0.z * b0.z + b0.w * b0.w
                 + b1.x * b1.x + b1.y * b1.y + b1.z * b1.z + b1.w * b1.w;
        float dd = a0.x * b0.x + a0.y * b0.y + a0.z * b0.z + a0.w * b0.w
                 + a1.x * b1.x + a1.y * b1.y + a1.z * b1.z + a1.w * b1.w;
        for (int m = 1; m < 64; m <<= 1) {
            si += __shfl_xor(si, m);
            sj += __shfl_xor(sj, m);
            dd += __shfl_xor(dd, m);
        }
        if (l == 0) {
            float ni = sqrtf(si), nj = sqrtf(sj);
            ri_arr[row] = INV_T / fmaxf(ni, 1e-6f);   // norms ~22; eps never binds
            pos_arr[row] = dd / fmaxf(ni * nj, EPSV) * INV_T;
        }
        *(int2*)(A + (size_t)row * D_SZ + l * 8) = pack_fp8x8(a0, a1);
    } else {
        int g = (blockIdx.x - 2048) * 4 + w;        // 0..4095
        int c0 = perm[g >> 1];
        int c = c0 + (g & 1);                       // actual z_j row
        const float4* src = (const float4*)(zj + (size_t)c * D_SZ);
        float4 a0 = src[2 * l], a1 = src[2 * l + 1];
        float s = a0.x * a0.x + a0.y * a0.y + a0.z * a0.z + a0.w * a0.w
                + a1.x * a1.x + a1.y * a1.y + a1.z * a1.z + a1.w * a1.w;
        for (int m = 1; m < 64; m <<= 1) s += __shfl_xor(s, m);
        if (l == 0)
            gmeta[g] = make_float2(1.0f / fmaxf(sqrtf(s), 1e-6f),
                                   __int_as_float(c0));
        *(int2*)(G + (size_t)g * D_SZ + l * 8) = pack_fp8x8(a0, a1);
    }
}

// ---------------------------------------------------------------------------
// Kernel 2: MX-fp8 MFMA GEMM, TRANSPOSED OUTPUT: S^T = G (4096x512) . A^T.
// v_mfma_scale_f32_32x32x64_f8f6f4, unit scales (numerically = plain e4m3).
// KEY LAYOUT TRICK: with G as the M-operand and A as the N-operand, the
// 32x32 C/D layout puts anchor = col = lane, g = row = reg. Each lane's 16
// regs are 16 negatives of the SAME anchor -> the sum-exp/count reduction is
// pure in-register accumulation; cross-lane work is ONE xor-32 shfl per tn
// (vs 320 ds_swizzles in the row-major version, which were the LDS-pipe
// bottleneck: ~26 us/CU serialized).
// 128x128 tile, BK=64, 256 threads (2x2 waves), dbuf LDS 2x(8+8) KB,
// 16B-chunk swizzle slot = c ^ ((r^(r>>2))&3) (measured 0 conflicts).
// XCD-aware mapping: xcd = bid&7 owns a 512-row G slab (L2-resident) and
// walks all 64 anchor-panels in lockstep with the other XCDs.
// ---------------------------------------------------------------------------
__global__ __launch_bounds__(256, 3) void k_gemm(
    const unsigned char* __restrict__ A,    // [8192][512] fp8  (anchors)
    const unsigned char* __restrict__ G,    // [4096][512] fp8  (gathered)
    const float2* __restrict__ gmeta,       // [4096]  {1/nj, bitcast(c0)}
    const float* __restrict__ ri_arr,       // [8192]  INV_T/ni
    const float* __restrict__ pos_arr,      // [8192]
    float* __restrict__ ws_pe, float* __restrict__ ws_pc)  // [8192][64]
{
    __shared__ unsigned char Asl[2][128 * 64];   // anchor tile, 8 KB per buffer
    __shared__ unsigned char Gsl[2][128 * 64];   // g tile
    const int tid = threadIdx.x;
    const int l = tid & 63, w = tid >> 6;
    const int wm = w >> 1, wn = w & 1;      // wm: g-half, wn: anchor-half
    const int ln = l & 31, q = l >> 5;      // 32x32 MFMA lane decomposition

    // XCD-aware tile mapping: 2048 blocks; xcd = bid&7 owns g-slab xcd*4..+4
    const int bid = blockIdx.x;
    const int xcd = bid & 7;
    const int slot = bid >> 3;              // 0..255
    const int gTile = xcd * 4 + (slot & 3); // 0..31 (G row panel)
    const int aTile = slot >> 2;            // 0..63 (anchor panel)
    const int gBase = gTile * 128;
    const int aBase = aTile * 128;

    // staging offsets (bytes); 512 16B-chunks per array per dblk (2 iters x 256)
    size_t aOff[2], gOff[2];
    int ldsOff[2];
    #pragma unroll
    for (int it = 0; it < 2; ++it) {
        int fc = it * 256 + tid;            // 16B chunk 0..511
        int r = fc >> 2, s = fc & 3;
        int scc = s ^ ((r ^ (r >> 2)) & 3); // XOR swizzle source 16B chunk
        aOff[it] = (size_t)(aBase + r) * D_SZ + scc * 16;
        gOff[it] = (size_t)(gBase + r) * D_SZ + scc * 16;
        ldsOff[it] = fc * 16;
    }

    floatx16 acc[2][2] = {};                // [tm: g-subtile][tn: anchor-subtile]

    // frag read addresses (bytes in an 8 KB buffer): lane needs k-bytes
    // [q*32, q*32+32) of its row = pre-swizzle chunks {2q, 2q+1}
    int aAddr[2][2], gAddr[2][2];           // [t][chunk half]
    #pragma unroll
    for (int t = 0; t < 2; ++t) {
        int ar = wn * 64 + t * 32 + ln;     // anchor row (N-operand)
        int xa = (ar ^ (ar >> 2)) & 3;
        aAddr[t][0] = ar * 64 + ((2 * q) ^ xa) * 16;
        aAddr[t][1] = ar * 64 + ((2 * q + 1) ^ xa) * 16;
        int gr = wm * 64 + t * 32 + ln;     // g row (M-operand)
        int xg = (gr ^ (gr >> 2)) & 3;
        gAddr[t][0] = gr * 64 + ((2 * q) ^ xg) * 16;
        gAddr[t][1] = gr * 64 + ((2 * q + 1) ^ xg) * 16;
    }

    // prologue: stage k-block 0 into buffer 0
    #pragma unroll
    for (int it = 0; it < 2; ++it) {
        async_cp16(A + aOff[it], &Asl[0][ldsOff[it]]);
        async_cp16(G + gOff[it], &Gsl[0][ldsOff[it]]);
    }

    #pragma unroll 1
    for (int dblk = 0; dblk < 8; ++dblk) {
        const int cur = dblk & 1, nxt = cur ^ 1;
        __syncthreads();                    // staged data for `cur` is ready
        if (dblk < 7) {
            #pragma unroll
            for (int it = 0; it < 2; ++it) {
                async_cp16(A + aOff[it] + (size_t)(dblk + 1) * 64, &Asl[nxt][ldsOff[it]]);
                async_cp16(G + gOff[it] + (size_t)(dblk + 1) * 64, &Gsl[nxt][ldsOff[it]]);
            }
        }
        intx8 af[2], gf[2];
        #pragma unroll
        for (int t = 0; t < 2; ++t) {
            int4 lo = *(const int4*)&Asl[cur][aAddr[t][0]];
            int4 hi = *(const int4*)&Asl[cur][aAddr[t][1]];
            af[t][0] = lo.x; af[t][1] = lo.y; af[t][2] = lo.z; af[t][3] = lo.w;
            af[t][4] = hi.x; af[t][5] = hi.y; af[t][6] = hi.z; af[t][7] = hi.w;
            int4 glo = *(const int4*)&Gsl[cur][gAddr[t][0]];
            int4 ghi = *(const int4*)&Gsl[cur][gAddr[t][1]];
            gf[t][0] = glo.x; gf[t][1] = glo.y; gf[t][2] = glo.z; gf[t][3] = glo.w;
            gf[t][4] = ghi.x; gf[t][5] = ghi.y; gf[t][6] = ghi.z; gf[t][7] = ghi.w;
        }
        #pragma unroll
        for (int tm = 0; tm < 2; ++tm)
            #pragma unroll
            for (int tn = 0; tn < 2; ++tn)
                acc[tm][tn] = __builtin_amdgcn_mfma_scale_f32_32x32x64_f8f6f4(
                    gf[tm], af[tn], acc[tm][tn],
                    0, 0,                       // cbsz/blgp = fp8 e4m3
                    0, 0x7f7f7f7f,              // scale A: all-ones (2^0)
                    0, 0x7f7f7f7f);             // scale B: all-ones (2^0)
    }

    // ---- fused epilogue: per-lane in-register reduction over g (= regs) ----
    // C/D layout (32x32): col = anchor = ln (+tn*32), row = g = (reg&3) +
    // 8*(reg>>2) + 4*q (+tm*32). One xor-32 shfl merges the q-halves.
    const int cb = gTile * 2 + wm;          // 64-g-chunk index, 0..63
    int anc[2]; float riv[2], pv[2], pe[2] = {0.f, 0.f}, pc[2] = {0.f, 0.f};
    #pragma unroll
    for (int tn = 0; tn < 2; ++tn) {
        anc[tn] = aBase + wn * 64 + tn * 32 + ln;
        riv[tn] = ri_arr[anc[tn]];          // INV_T / ni
        pv[tn] = pos_arr[anc[tn]];
    }
    #pragma unroll
    for (int tm = 0; tm < 2; ++tm) {
        #pragma unroll
        for (int reg = 0; reg < 16; ++reg) {
            int g = gBase + wm * 64 + tm * 32 + (reg & 3) + 8 * (reg >> 2) + 4 * q;
            float2 md = gmeta[g];
            float rj = md.x;
            int c0 = __float_as_int(md.y);
            int shv = g & 1;
            #pragma unroll
            for (int tn = 0; tn < 2; ++tn) {
                float logit = acc[tm][tn][reg] * riv[tn] * rj;
                // anchor i uses col c0+1 iff c0 >= i; our g holds c0+shv
                bool use = ((c0 >= anc[tn]) ? 1 : 0) == shv;
                pe[tn] += use ? __expf(logit) : 0.f;
                pc[tn] += (use && logit > pv[tn]) ? 1.f : 0.f;
            }
        }
    }
    #pragma unroll
    for (int tn = 0; tn < 2; ++tn) {
        pe[tn] += __shfl_xor(pe[tn], 32);
        pc[tn] += __shfl_xor(pc[tn], 32);
        if (q == 0) {
            ws_pe[(size_t)anc[tn] * 64 + cb] = pe[tn];
            ws_pc[(size_t)anc[tn] * 64 + cb] = pc[tn];
        }
    }
}

// ---------------------------------------------------------------------------
// Kernel 3: per-row finalize + global reduction into d_out[3].
// Wave-per-row: 128 blocks x 256 threads, 64 rows per block (16 rows/wave).
// ---------------------------------------------------------------------------
__global__ __launch_bounds__(256) void k_final(
    const float* __restrict__ ws_pe, const float* __restrict__ ws_pc,
    const float* __restrict__ pos_arr, float* __restrict__ out)
{
    int w = threadIdx.x >> 6, l = threadIdx.x & 63;
    float lsum = 0.f, a1sum = 0.f, a5sum = 0.f;
    #pragma unroll 4
    for (int j = 0; j < 16; ++j) {
        int row = blockIdx.x * 64 + j * 4 + w;
        float pe = ws_pe[(size_t)row * 64 + l];
        float pc = ws_pc[(size_t)row * 64 + l];
        for (int m = 1; m < 64; m <<= 1) {
            pe += __shfl_xor(pe, m);
            pc += __shfl_xor(pc, m);
        }
        if (l == 0) {
            float pos = pos_arr[row];
            lsum += logf(__expf(pos) + pe) - pos;   // logsumexp - pos (logits bounded)
            a1sum += (pc < 0.5f) ? 1.f : 0.f;       // no neg strictly > pos
            a5sum += (pc < 4.5f) ? 1.f : 0.f;       // at most 4 negs strictly > pos
        }
    }
    __shared__ float red[3][4];
    if (l == 0) { red[0][w] = lsum; red[1][w] = a1sum; red[2][w] = a5sum; }
    __syncthreads();
    if (threadIdx.x == 0) {
        float L = red[0][0] + red[0][1] + red[0][2] + red[0][3];
        float A1 = red[1][0] + red[1][1] + red[1][2] + red[1][3];
        float A5 = red[2][0] + red[2][1] + red[2][2] + red[2][3];
        atomicAdd(&out[0], L / (float)B_SZ);
        atomicAdd(&out[1], A1 * (100.f / (float)B_SZ));
        atomicAdd(&out[2], A5 * (100.f / (float)B_SZ));
    }
}

// ---------------------------------------------------------------------------
extern "C" void kernel_launch(void* const* d_in, const int* in_sizes, int n_in,
                              void* d_out, int out_size, void* d_ws, size_t ws_size,
                              hipStream_t stream)
{
    const float* zi = (const float*)d_in[0];
    const float* zj = (const float*)d_in[1];
    const int* perm = (const int*)d_in[2];
    float* out = (float*)d_out;

    // workspace layout (all 16B aligned)
    char* p = (char*)d_ws;
    unsigned char* A = (unsigned char*)p;    p += (size_t)B_SZ * D_SZ;          // 4 MB
    unsigned char* G = (unsigned char*)p;    p += (size_t)2 * K_SZ * D_SZ;      // 2 MB
    float* ri_arr = (float*)p;               p += (size_t)B_SZ * 4;
    float* pos_arr = (float*)p;              p += (size_t)B_SZ * 4;
    float2* gmeta = (float2*)p;              p += (size_t)2 * K_SZ * 8;
    float* ws_pe = (float*)p;                p += (size_t)B_SZ * 64 * 4;        // 2 MB
    float* ws_pc = (float*)p;                p += (size_t)B_SZ * 64 * 4;        // 2 MB

    hipMemsetAsync(d_out, 0, 3 * sizeof(float), stream);

    k_prep<<<2048 + 1024, 256, 0, stream>>>(zi, zj, perm, ri_arr, pos_arr, A, gmeta, G);
    k_gemm<<<2048, 256, 0, stream>>>(A, G, gmeta, ri_arr, pos_arr, ws_pe, ws_pc);
    k_final<<<128, 256, 0, stream>>>(ws_pe, ws_pc, pos_arr, out);
}

// Round 10
// 123.599 us; speedup vs baseline: 1.9368x; 1.0142x over previous
//
#include <hip/hip_runtime.h>
#include <cstdint>

#define B_SZ 8192
#define D_SZ 512
#define K_SZ 2048
#define EPSV 1e-8f
// 1/TEMP
#define INV_T 2.0f

typedef float floatx16 __attribute__((ext_vector_type(16)));
typedef int intx8 __attribute__((ext_vector_type(8)));

// async global->LDS, 16B per lane. LDS dest must be wave-uniform base + lane*16.
__device__ __forceinline__ void async_cp16(const void* g, void* l) {
    typedef __attribute__((address_space(1))) unsigned int gds_t;
    typedef __attribute__((address_space(3))) unsigned int lds_t;
    __builtin_amdgcn_global_load_lds((gds_t*)(unsigned long long)g, (lds_t*)l, 16, 0, 0);
}

// pack 8 fp32 -> 8 fp8 e4m3 (OCP, RNE, saturating) as int2
__device__ __forceinline__ int2 pack_fp8x8(float4 a0, float4 a1) {
    int w0 = __builtin_amdgcn_cvt_pk_fp8_f32(a0.x, a0.y, 0, false);
    w0 = __builtin_amdgcn_cvt_pk_fp8_f32(a0.z, a0.w, w0, true);
    int w1 = __builtin_amdgcn_cvt_pk_fp8_f32(a1.x, a1.y, 0, false);
    w1 = __builtin_amdgcn_cvt_pk_fp8_f32(a1.z, a1.w, w1, true);
    return make_int2(w0, w1);
}

// ---------------------------------------------------------------------------
// Kernel 1 (merged prep+gather):
//  blocks [0,2048):  per-row norms of z_i/z_j, positive logit, z_i -> fp8 A
//  blocks [2048,3072): gather 2K=4096 rows (c_k, c_k+1) of z_j -> fp8 G,
//    plus PER-COLUMN-PAIR metadata kmeta[k] = {1/nj(c), 1/nj(c+1), c0} so the
//    GEMM epilogue selects-then-exps (one exp per used logit).
//  Block 0 zeroes d_out (replaces a separate memset dispatch).
// ---------------------------------------------------------------------------
__global__ __launch_bounds__(256) void k_prep(
    const float* __restrict__ zi, const float* __restrict__ zj,
    const int* __restrict__ perm,
    float* __restrict__ ri_arr, float* __restrict__ pos_arr,
    unsigned char* __restrict__ A,
    float4* __restrict__ kmeta, unsigned char* __restrict__ G,
    float* __restrict__ out)
{
    int w = threadIdx.x >> 6, l = threadIdx.x & 63;
    if (blockIdx.x < 2048) {
        if (blockIdx.x == 0 && threadIdx.x < 3) out[threadIdx.x] = 0.f;
        int row = blockIdx.x * 4 + w;
        const float4* zi4 = (const float4*)(zi + (size_t)row * D_SZ);
        const float4* zj4 = (const float4*)(zj + (size_t)row * D_SZ);
        float4 a0 = zi4[2 * l], a1 = zi4[2 * l + 1];
        float4 b0 = zj4[2 * l], b1 = zj4[2 * l + 1];
        float si = a0.x * a0.x + a0.y * a0.y + a0.z * a0.z + a0.w * a0.w
                 + a1.x * a1.x + a1.y * a1.y + a1.z * a1.z + a1.w * a1.w;
        float sj = b0.x * b0.x + b0.y * b0.y + b0.z * b0.z + b0.w * b0.w
                 + b1.x * b1.x + b1.y * b1.y + b1.z * b1.z + b1.w * b1.w;
        float dd = a0.x * b0.x + a0.y * b0.y + a0.z * b0.z + a0.w * b0.w
                 + a1.x * b1.x + a1.y * b1.y + a1.z * b1.z + a1.w * b1.w;
        for (int m = 1; m < 64; m <<= 1) {
            si += __shfl_xor(si, m);
            sj += __shfl_xor(sj, m);
            dd += __shfl_xor(dd, m);
        }
        if (l == 0) {
            float ni = sqrtf(si), nj = sqrtf(sj);
            ri_arr[row] = INV_T / fmaxf(ni, 1e-6f);   // norms ~22; eps never binds
            pos_arr[row] = dd / fmaxf(ni * nj, EPSV) * INV_T;
        }
        *(int2*)(A + (size_t)row * D_SZ + l * 8) = pack_fp8x8(a0, a1);
    } else {
        __shared__ float srj[4];
        int g = (blockIdx.x - 2048) * 4 + w;        // 0..4095
        int c0 = perm[g >> 1];
        int c = c0 + (g & 1);                       // actual z_j row
        const float4* src = (const float4*)(zj + (size_t)c * D_SZ);
        float4 a0 = src[2 * l], a1 = src[2 * l + 1];
        float s = a0.x * a0.x + a0.y * a0.y + a0.z * a0.z + a0.w * a0.w
                + a1.x * a1.x + a1.y * a1.y + a1.z * a1.z + a1.w * a1.w;
        for (int m = 1; m < 64; m <<= 1) s += __shfl_xor(s, m);
        if (l == 0) srj[w] = 1.0f / fmaxf(sqrtf(s), 1e-6f);
        __syncthreads();
        if ((w & 1) == 0 && l == 0)
            kmeta[g >> 1] = make_float4(srj[w], srj[w + 1],
                                        __int_as_float(c0), 0.f);
        *(int2*)(G + (size_t)g * D_SZ + l * 8) = pack_fp8x8(a0, a1);
    }
}

// ---------------------------------------------------------------------------
// Kernel 2: MX-fp8 MFMA GEMM, TRANSPOSED OUTPUT: S^T = G (4096x512) . A^T.
// v_mfma_scale_f32_32x32x64_f8f6f4, unit scales (numerically = plain e4m3).
// Transposed layout: anchor = col = lane, g = row = reg -> sum-exp/count
// reduction is in-register; one xor-32 shfl per tn.
// PAIR-SELECT EPILOGUE: the two candidate rows of column k (g=2k, 2k+1) are
// ADJACENT regs of the same lane; select by (c0 >= anchor) via cndmask, then
// ONE exp -> 32 exps/lane instead of 64, no mask logic, one float4 meta/pair.
// 128x128 tile, BK=64, 256 threads (2x2 waves), dbuf LDS 2x(8+8) KB,
// 16B-chunk swizzle slot = c ^ ((r^(r>>2))&3) (measured 0 conflicts).
// __launch_bounds__(256,4): 60 arch VGPR + 64 acc = 124 unified <= 128 ->
// 4 blocks/CU (was 3).
// XCD-aware mapping: xcd = bid&7 owns a 512-row G slab (L2-resident).
// ---------------------------------------------------------------------------
__global__ __launch_bounds__(256, 4) void k_gemm(
    const unsigned char* __restrict__ A,    // [8192][512] fp8  (anchors)
    const unsigned char* __restrict__ G,    // [4096][512] fp8  (gathered)
    const float4* __restrict__ kmeta,       // [2048]  {rj0, rj1, c0f, -}
    const float* __restrict__ ri_arr,       // [8192]  INV_T/ni
    const float* __restrict__ pos_arr,      // [8192]
    float* __restrict__ ws_pe, float* __restrict__ ws_pc)  // [8192][64]
{
    __shared__ unsigned char Asl[2][128 * 64];   // anchor tile, 8 KB per buffer
    __shared__ unsigned char Gsl[2][128 * 64];   // g tile
    const int tid = threadIdx.x;
    const int l = tid & 63, w = tid >> 6;
    const int wm = w >> 1, wn = w & 1;      // wm: g-half, wn: anchor-half
    const int ln = l & 31, q = l >> 5;      // 32x32 MFMA lane decomposition

    // XCD-aware tile mapping: 2048 blocks; xcd = bid&7 owns g-slab xcd*4..+4
    const int bid = blockIdx.x;
    const int xcd = bid & 7;
    const int slot = bid >> 3;              // 0..255
    const int gTile = xcd * 4 + (slot & 3); // 0..31 (G row panel)
    const int aTile = slot >> 2;            // 0..63 (anchor panel)
    const int gBase = gTile * 128;
    const int aBase = aTile * 128;

    // staging offsets (bytes); 512 16B-chunks per array per dblk (2 iters x 256)
    size_t aOff[2], gOff[2];
    int ldsOff[2];
    #pragma unroll
    for (int it = 0; it < 2; ++it) {
        int fc = it * 256 + tid;            // 16B chunk 0..511
        int r = fc >> 2, s = fc & 3;
        int scc = s ^ ((r ^ (r >> 2)) & 3); // XOR swizzle source 16B chunk
        aOff[it] = (size_t)(aBase + r) * D_SZ + scc * 16;
        gOff[it] = (size_t)(gBase + r) * D_SZ + scc * 16;
        ldsOff[it] = fc * 16;
    }

    floatx16 acc[2][2] = {};                // [tm: g-subtile][tn: anchor-subtile]

    // frag read addresses (bytes in an 8 KB buffer): lane needs k-bytes
    // [q*32, q*32+32) of its row = pre-swizzle chunks {2q, 2q+1}
    int aAddr[2][2], gAddr[2][2];           // [t][chunk half]
    #pragma unroll
    for (int t = 0; t < 2; ++t) {
        int ar = wn * 64 + t * 32 + ln;     // anchor row (N-operand)
        int xa = (ar ^ (ar >> 2)) & 3;
        aAddr[t][0] = ar * 64 + ((2 * q) ^ xa) * 16;
        aAddr[t][1] = ar * 64 + ((2 * q + 1) ^ xa) * 16;
        int gr = wm * 64 + t * 32 + ln;     // g row (M-operand)
        int xg = (gr ^ (gr >> 2)) & 3;
        gAddr[t][0] = gr * 64 + ((2 * q) ^ xg) * 16;
        gAddr[t][1] = gr * 64 + ((2 * q + 1) ^ xg) * 16;
    }

    // prologue: stage k-block 0 into buffer 0
    #pragma unroll
    for (int it = 0; it < 2; ++it) {
        async_cp16(A + aOff[it], &Asl[0][ldsOff[it]]);
        async_cp16(G + gOff[it], &Gsl[0][ldsOff[it]]);
    }

    #pragma unroll 1
    for (int dblk = 0; dblk < 8; ++dblk) {
        const int cur = dblk & 1, nxt = cur ^ 1;
        __syncthreads();                    // staged data for `cur` is ready
        if (dblk < 7) {
            #pragma unroll
            for (int it = 0; it < 2; ++it) {
                async_cp16(A + aOff[it] + (size_t)(dblk + 1) * 64, &Asl[nxt][ldsOff[it]]);
                async_cp16(G + gOff[it] + (size_t)(dblk + 1) * 64, &Gsl[nxt][ldsOff[it]]);
            }
        }
        intx8 af[2], gf[2];
        #pragma unroll
        for (int t = 0; t < 2; ++t) {
            int4 lo = *(const int4*)&Asl[cur][aAddr[t][0]];
            int4 hi = *(const int4*)&Asl[cur][aAddr[t][1]];
            af[t][0] = lo.x; af[t][1] = lo.y; af[t][2] = lo.z; af[t][3] = lo.w;
            af[t][4] = hi.x; af[t][5] = hi.y; af[t][6] = hi.z; af[t][7] = hi.w;
            int4 glo = *(const int4*)&Gsl[cur][gAddr[t][0]];
            int4 ghi = *(const int4*)&Gsl[cur][gAddr[t][1]];
            gf[t][0] = glo.x; gf[t][1] = glo.y; gf[t][2] = glo.z; gf[t][3] = glo.w;
            gf[t][4] = ghi.x; gf[t][5] = ghi.y; gf[t][6] = ghi.z; gf[t][7] = ghi.w;
        }
        #pragma unroll
        for (int tm = 0; tm < 2; ++tm)
            #pragma unroll
            for (int tn = 0; tn < 2; ++tn)
                acc[tm][tn] = __builtin_amdgcn_mfma_scale_f32_32x32x64_f8f6f4(
                    gf[tm], af[tn], acc[tm][tn],
                    0, 0,                       // cbsz/blgp = fp8 e4m3
                    0, 0x7f7f7f7f,              // scale A: all-ones (2^0)
                    0, 0x7f7f7f7f);             // scale B: all-ones (2^0)
    }

    // ---- fused epilogue: pair-select then exp, in-register reduction ----
    // C/D layout (32x32): col = anchor = ln (+tn*32), row = g = (reg&3) +
    // 8*(reg>>2) + 4*q (+tm*32). Regs 4j..4j+3 hold 4 consecutive g, i.e.
    // column pairs k0 = gTile*64 + wm*32 + tm*16 + 4j + 2q and k0+1.
    const int cb = gTile * 2 + wm;          // 64-g-chunk index, 0..63
    int anc[2]; float riv[2], pv[2], pe[2] = {0.f, 0.f}, pc[2] = {0.f, 0.f};
    #pragma unroll
    for (int tn = 0; tn < 2; ++tn) {
        anc[tn] = aBase + wn * 64 + tn * 32 + ln;
        riv[tn] = ri_arr[anc[tn]];          // INV_T / ni
        pv[tn] = pos_arr[anc[tn]];
    }
    #pragma unroll
    for (int tm = 0; tm < 2; ++tm) {
        #pragma unroll
        for (int j = 0; j < 4; ++j) {
            int k0 = gTile * 64 + wm * 32 + tm * 16 + 4 * j + 2 * q;
            float4 m0 = kmeta[k0];
            float4 m1 = kmeta[k0 + 1];
            #pragma unroll
            for (int p = 0; p < 2; ++p) {
                float4 md = p ? m1 : m0;
                int c0 = __float_as_int(md.z);
                int re = 4 * j + 2 * p;     // even-g reg; odd is re+1
                #pragma unroll
                for (int tn = 0; tn < 2; ++tn) {
                    bool sel = (c0 >= anc[tn]);             // use column c0+1
                    float v = sel ? acc[tm][tn][re + 1] : acc[tm][tn][re];
                    float rj = sel ? md.y : md.x;
                    float logit = v * riv[tn] * rj;
                    pe[tn] += __expf(logit);
                    pc[tn] += (logit > pv[tn]) ? 1.f : 0.f;
                }
            }
        }
    }
    #pragma unroll
    for (int tn = 0; tn < 2; ++tn) {
        pe[tn] += __shfl_xor(pe[tn], 32);
        pc[tn] += __shfl_xor(pc[tn], 32);
        if (q == 0) {
            ws_pe[(size_t)anc[tn] * 64 + cb] = pe[tn];
            ws_pc[(size_t)anc[tn] * 64 + cb] = pc[tn];
        }
    }
}

// ---------------------------------------------------------------------------
// Kernel 3: per-row finalize + global reduction into d_out[3].
// Wave-per-row: 128 blocks x 256 threads, 64 rows per block (16 rows/wave).
// ---------------------------------------------------------------------------
__global__ __launch_bounds__(256) void k_final(
    const float* __restrict__ ws_pe, const float* __restrict__ ws_pc,
    const float* __restrict__ pos_arr, float* __restrict__ out)
{
    int w = threadIdx.x >> 6, l = threadIdx.x & 63;
    float lsum = 0.f, a1sum = 0.f, a5sum = 0.f;
    #pragma unroll 4
    for (int j = 0; j < 16; ++j) {
        int row = blockIdx.x * 64 + j * 4 + w;
        float pe = ws_pe[(size_t)row * 64 + l];
        float pc = ws_pc[(size_t)row * 64 + l];
        for (int m = 1; m < 64; m <<= 1) {
            pe += __shfl_xor(pe, m);
            pc += __shfl_xor(pc, m);
        }
        if (l == 0) {
            float pos = pos_arr[row];
            lsum += logf(__expf(pos) + pe) - pos;   // logsumexp - pos (logits bounded)
            a1sum += (pc < 0.5f) ? 1.f : 0.f;       // no neg strictly > pos
            a5sum += (pc < 4.5f) ? 1.f : 0.f;       // at most 4 negs strictly > pos
        }
    }
    __shared__ float red[3][4];
    if (l == 0) { red[0][w] = lsum; red[1][w] = a1sum; red[2][w] = a5sum; }
    __syncthreads();
    if (threadIdx.x == 0) {
        float L = red[0][0] + red[0][1] + red[0][2] + red[0][3];
        float A1 = red[1][0] + red[1][1] + red[1][2] + red[1][3];
        float A5 = red[2][0] + red[2][1] + red[2][2] + red[2][3];
        atomicAdd(&out[0], L / (float)B_SZ);
        atomicAdd(&out[1], A1 * (100.f / (float)B_SZ));
        atomicAdd(&out[2], A5 * (100.f / (float)B_SZ));
    }
}

// ---------------------------------------------------------------------------
extern "C" void kernel_launch(void* const* d_in, const int* in_sizes, int n_in,
                              void* d_out, int out_size, void* d_ws, size_t ws_size,
                              hipStream_t stream)
{
    const float* zi = (const float*)d_in[0];
    const float* zj = (const float*)d_in[1];
    const int* perm = (const int*)d_in[2];
    float* out = (float*)d_out;

    // workspace layout (all 16B aligned)
    char* p = (char*)d_ws;
    unsigned char* A = (unsigned char*)p;    p += (size_t)B_SZ * D_SZ;          // 4 MB
    unsigned char* G = (unsigned char*)p;    p += (size_t)2 * K_SZ * D_SZ;      // 2 MB
    float* ri_arr = (float*)p;               p += (size_t)B_SZ * 4;
    float* pos_arr = (float*)p;              p += (size_t)B_SZ * 4;
    float4* kmeta = (float4*)p;              p += (size_t)K_SZ * 16;            // 32 KB
    float* ws_pe = (float*)p;                p += (size_t)B_SZ * 64 * 4;        // 2 MB
    float* ws_pc = (float*)p;                p += (size_t)B_SZ * 64 * 4;        // 2 MB

    k_prep<<<2048 + 1024, 256, 0, stream>>>(zi, zj, perm, ri_arr, pos_arr, A,
                                            kmeta, G, out);
    k_gemm<<<2048, 256, 0, stream>>>(A, G, kmeta, ri_arr, pos_arr, ws_pe, ws_pc);
    k_final<<<128, 256, 0, stream>>>(ws_pe, ws_pc, pos_arr, out);
}